// Round 6
// baseline (248.389 us; speedup 1.0000x reference)
//
#include <hip/hip_runtime.h>
#include <cstdint>
#include <cstddef>

// GraphSAGE 2-layer forward, mean aggregation. R6: nontemporal slot scatter,
// dense split gather buffers (xbf/aggx/grL/grR), batch-8 gather ILP.
//   layer1: h = relu( [agg(x)|x] @ [Wl1;Wr1] + b1 )   (bf16 MFMA)
//   layer2: grL|grR = h @ [Wl2|Wr2]                   (bf16 MFMA)
//           out[i] = sigmoid( mean_agg(grL)[i] + grR[i] + b2 )

#define N_NODES 50000
#define N_EDGES 800000
#define F_IN 128
#define F_HID 256
#define F_OUT 64
#define CAP 64  // slots per node; P(Poisson(16) >= 64) ~ 2e-22 per node

typedef __attribute__((ext_vector_type(8))) short bf16x8;
typedef __attribute__((ext_vector_type(4))) float f32x4;

__device__ inline unsigned short f2bf(float f) {  // RNE
    unsigned int u = __float_as_uint(f);
    u += 0x7fffu + ((u >> 16) & 1u);
    return (unsigned short)(u >> 16);
}
__device__ inline unsigned int pack_bf2(float lo, float hi) {
    return (unsigned int)f2bf(lo) | ((unsigned int)f2bf(hi) << 16);
}
__device__ inline float bf_lo(unsigned int u) { return __uint_as_float(u << 16); }
__device__ inline float bf_hi(unsigned int u) { return __uint_as_float(u & 0xffff0000u); }
__device__ inline float bfs(unsigned short s) { return __uint_as_float((unsigned int)s << 16); }

// ---------------- bucket build (single pass, nt scatter) ----------------
__global__ void bucket_slots_kernel(const int* __restrict__ src, const int* __restrict__ dst,
                                    int* __restrict__ cnt, unsigned short* __restrict__ slots,
                                    int E) {
    int e = blockIdx.x * blockDim.x + threadIdx.x;
    if (e < E) {
        int d = dst[e];
        int p = atomicAdd(&cnt[d], 1);
        if (p < CAP)
            __builtin_nontemporal_store((unsigned short)src[e], &slots[(size_t)d * CAP + p]);
    }
}

// ---------------- prep: fp32 -> bf16 conversions ----------------

// x [N x 128] fp32 -> dense bf16 xbf (uint-packed, 64 uints/row)
__global__ void prep_x_kernel(const float* __restrict__ x, unsigned int* __restrict__ xbf) {
    int i = blockIdx.x * blockDim.x + threadIdx.x;  // over N_NODES*64
    if (i >= N_NODES * 64) return;
    int row = i >> 6, c = i & 63;
    float2 f = *reinterpret_cast<const float2*>(&x[(size_t)row * F_IN + 2 * c]);
    xbf[(size_t)row * 64 + c] = pack_bf2(f.x, f.y);
}

// Bt1[n][k] (256x256): k<128 -> Wl1[k][n], else Wr1[k-128][n]
// Bt2[n][k] (128x256): n<64 -> Wl2[k][n], else Wr2[k][n-64]
__global__ void prep_w_kernel(const float* __restrict__ Wl1, const float* __restrict__ Wr1,
                              const float* __restrict__ Wl2, const float* __restrict__ Wr2,
                              short* __restrict__ Bt1, short* __restrict__ Bt2) {
    int i = blockIdx.x * blockDim.x + threadIdx.x;
    if (i < 256 * 256) {
        int k = i >> 8, n = i & 255;
        float v = (k < 128) ? Wl1[k * 256 + n] : Wr1[(k - 128) * 256 + n];
        Bt1[n * 256 + k] = (short)f2bf(v);
    } else if (i < 256 * 256 + 128 * 256) {
        int i2 = i - 256 * 256;
        int k = i2 >> 7, n = i2 & 127;
        float v = (n < 64) ? Wl2[k * 64 + n] : Wr2[k * 64 + (n - 64)];
        Bt2[n * 256 + k] = (short)f2bf(v);
    }
}

// ---------------- layer-1 mean aggregation (dense bf16 gather, fp32 acc) ----------------
__global__ __launch_bounds__(256) void agg1_kernel(const unsigned int* __restrict__ xbf,
                                                   unsigned int* __restrict__ aggx,
                                                   const int* __restrict__ cnt,
                                                   const unsigned short* __restrict__ slots) {
    const int node = blockIdx.x * 4 + (threadIdx.x >> 6);
    const int t = threadIdx.x & 63;
    if (node >= N_NODES) return;
    const int deg = cnt[node];
    const int n = min(deg, CAP);
    const unsigned short* sl = &slots[(size_t)node * CAP];
    float a0 = 0.f, a1 = 0.f;
    int j = 0;
    for (; j + 8 <= n; j += 8) {
        unsigned int u[8];
#pragma unroll
        for (int q = 0; q < 8; ++q) u[q] = xbf[(size_t)sl[j + q] * 64 + t];
#pragma unroll
        for (int q = 0; q < 8; ++q) {
            a0 += bf_lo(u[q]);
            a1 += bf_hi(u[q]);
        }
    }
    for (; j < n; ++j) {
        unsigned int u = xbf[(size_t)sl[j] * 64 + t];
        a0 += bf_lo(u);
        a1 += bf_hi(u);
    }
    float scale = (deg > 0) ? 1.0f / (float)deg : 0.0f;
    aggx[(size_t)node * 64 + t] = pack_bf2(a0 * scale, a1 * scale);
}

// ---------------- bf16 MFMA GEMM: C = act([A0|A1] @ Bt^T + bias) ----------------
// ASPLIT=1: A row = [A0 row (128, dense) | A1 row (128, dense)]; else A0 stride K.
// OSPLIT=1: output N=128 split to CL (n<64) / CR (n>=64), each stride 64;
// else single C = CL, stride N. ACT: 0 = bias+relu, 2 = identity.
template <int ACT, int ASPLIT, int OSPLIT>
__global__ __launch_bounds__(256) void gemm_mfma_kernel(int M, int N, int K,
                                                        const short* __restrict__ A0,
                                                        const short* __restrict__ A1,
                                                        const short* __restrict__ Bt,
                                                        const float* __restrict__ bias,
                                                        short* __restrict__ CL,
                                                        short* __restrict__ CR) {
    constexpr int BM = 128, BN = 128, BK = 64, LDK = BK + 8;  // pad 8 bf16
    __shared__ short As[BM * LDK];
    __shared__ short Bs[BN * LDK];

    const int tid = threadIdx.x;
    const int lane = tid & 63;
    const int wave = tid >> 6;
    const int quad = lane >> 4;
    const int l16 = lane & 15;
    const int m0 = blockIdx.y * BM;
    const int n0 = blockIdx.x * BN;
    const int wm0 = (wave >> 1) * 64;
    const int wn0 = (wave & 1) * 64;

    const int srow = tid >> 1;        // staging row 0..127
    const int scol = (tid & 1) * 32;  // 0 / 32 (bf16 units within BK chunk)

    f32x4 acc[4][4];
#pragma unroll
    for (int i = 0; i < 4; ++i)
#pragma unroll
        for (int j = 0; j < 4; ++j) acc[i][j] = (f32x4)(0.0f);

    for (int k0 = 0; k0 < K; k0 += BK) {
        {
            const int gm = m0 + srow;
            const int col = k0 + scol;  // 32-bf16 chunk start, fully inside one half
            uint4 v0, v1, v2, v3;
            if (gm < M) {
                const short* srcp;
                if (ASPLIT)
                    srcp = (col < 128) ? &A0[(size_t)gm * 128 + col]
                                       : &A1[(size_t)gm * 128 + (col - 128)];
                else
                    srcp = &A0[(size_t)gm * K + col];
                const uint4* s = reinterpret_cast<const uint4*>(srcp);
                v0 = s[0]; v1 = s[1]; v2 = s[2]; v3 = s[3];
            } else {
                v0 = v1 = v2 = v3 = make_uint4(0, 0, 0, 0);
            }
            uint4* d = reinterpret_cast<uint4*>(&As[srow * LDK + scol]);
            d[0] = v0; d[1] = v1; d[2] = v2; d[3] = v3;
        }
        {
            const uint4* s = reinterpret_cast<const uint4*>(&Bt[(size_t)(n0 + srow) * K + k0 + scol]);
            uint4 v0 = s[0], v1 = s[1], v2 = s[2], v3 = s[3];
            uint4* d = reinterpret_cast<uint4*>(&Bs[srow * LDK + scol]);
            d[0] = v0; d[1] = v1; d[2] = v2; d[3] = v3;
        }
        __syncthreads();
#pragma unroll
        for (int kk = 0; kk < BK; kk += 32) {
            bf16x8 af[4], bfr[4];
#pragma unroll
            for (int mi = 0; mi < 4; ++mi)
                af[mi] = *reinterpret_cast<const bf16x8*>(
                    &As[(wm0 + mi * 16 + l16) * LDK + kk + quad * 8]);
#pragma unroll
            for (int ni = 0; ni < 4; ++ni)
                bfr[ni] = *reinterpret_cast<const bf16x8*>(
                    &Bs[(wn0 + ni * 16 + l16) * LDK + kk + quad * 8]);
#pragma unroll
            for (int mi = 0; mi < 4; ++mi)
#pragma unroll
                for (int ni = 0; ni < 4; ++ni)
                    acc[mi][ni] = __builtin_amdgcn_mfma_f32_16x16x32_bf16(af[mi], bfr[ni],
                                                                          acc[mi][ni], 0, 0, 0);
        }
        __syncthreads();
    }

    // epilogue: C/D layout col=lane&15, row=quad*4+reg
#pragma unroll
    for (int mi = 0; mi < 4; ++mi) {
#pragma unroll
        for (int reg = 0; reg < 4; ++reg) {
            const int gm = m0 + wm0 + mi * 16 + quad * 4 + reg;
            if (gm >= M) continue;
#pragma unroll
            for (int ni = 0; ni < 4; ++ni) {
                const int gn = n0 + wn0 + ni * 16 + l16;
                float v = acc[mi][ni][reg];
                if (ACT == 0) {
                    v += bias[gn];
                    v = fmaxf(v, 0.0f);
                }
                short o = (short)f2bf(v);
                if (OSPLIT) {
                    if (gn < 64)
                        CL[(size_t)gm * 64 + gn] = o;
                    else
                        CR[(size_t)gm * 64 + (gn - 64)] = o;
                } else {
                    CL[(size_t)gm * N + gn] = o;
                }
            }
        }
    }
}

// ---------------- final: mean-agg over grL + grR self + bias, sigmoid ----------------
__global__ __launch_bounds__(256) void final_kernel(const unsigned short* __restrict__ grL,
                                                    const unsigned short* __restrict__ grR,
                                                    const int* __restrict__ cnt,
                                                    const unsigned short* __restrict__ slots,
                                                    const float* __restrict__ b2,
                                                    float* __restrict__ out) {
    const int node = blockIdx.x * 4 + (threadIdx.x >> 6);
    const int t = threadIdx.x & 63;
    if (node >= N_NODES) return;
    const int deg = cnt[node];
    const int n = min(deg, CAP);
    const unsigned short* sl = &slots[(size_t)node * CAP];
    float acc = 0.0f;
    int j = 0;
    for (; j + 8 <= n; j += 8) {
        unsigned short u[8];
#pragma unroll
        for (int q = 0; q < 8; ++q) u[q] = grL[(size_t)sl[j + q] * 64 + t];
#pragma unroll
        for (int q = 0; q < 8; ++q) acc += bfs(u[q]);
    }
    for (; j < n; ++j) acc += bfs(grL[(size_t)sl[j] * 64 + t]);
    float scale = (deg > 0) ? 1.0f / (float)deg : 0.0f;
    float v = acc * scale + bfs(grR[(size_t)node * 64 + t]) + b2[t];
    out[(size_t)node * F_OUT + t] = 1.0f / (1.0f + __expf(-v));
}

// ---------------- launch ----------------

extern "C" void kernel_launch(void* const* d_in, const int* in_sizes, int n_in,
                              void* d_out, int out_size, void* d_ws, size_t ws_size,
                              hipStream_t stream) {
    const float* x   = (const float*)d_in[0];
    const int* ei    = (const int*)d_in[1];
    const float* Wl1 = (const float*)d_in[2];
    const float* Wr1 = (const float*)d_in[3];
    const float* b1  = (const float*)d_in[4];
    const float* Wl2 = (const float*)d_in[5];
    const float* Wr2 = (const float*)d_in[6];
    const float* b2  = (const float*)d_in[7];
    float* out       = (float*)d_out;

    const int* src = ei;
    const int* dst = ei + N_EDGES;

    char* p = (char*)d_ws;
    auto alloc = [&](size_t bytes) {
        char* r = p;
        p += (bytes + 255) & ~(size_t)255;
        return (void*)r;
    };
    int* cnt              = (int*)alloc((size_t)N_NODES * 4);
    unsigned short* slots = (unsigned short*)alloc((size_t)N_NODES * CAP * 2);
    unsigned int* xbf     = (unsigned int*)alloc((size_t)N_NODES * 64 * 4);  // dense bf16 x
    unsigned int* aggx    = (unsigned int*)alloc((size_t)N_NODES * 64 * 4);  // dense bf16 agg
    short* h              = (short*)alloc((size_t)N_NODES * 256 * 2);
    short* grL            = (short*)alloc((size_t)N_NODES * 64 * 2);
    short* grR            = (short*)alloc((size_t)N_NODES * 64 * 2);
    short* Bt1            = (short*)alloc((size_t)256 * 256 * 2);
    short* Bt2            = (short*)alloc((size_t)128 * 256 * 2);
    (void)ws_size;

    // bucket build + prep conversions
    hipMemsetAsync(cnt, 0, (size_t)N_NODES * 4, stream);
    prep_x_kernel<<<(N_NODES * 64 + 255) / 256, 256, 0, stream>>>(x, xbf);
    bucket_slots_kernel<<<(N_EDGES + 255) / 256, 256, 0, stream>>>(src, dst, cnt, slots, N_EDGES);
    prep_w_kernel<<<(256 * 256 + 128 * 256 + 255) / 256, 256, 0, stream>>>(Wl1, Wr1, Wl2, Wr2,
                                                                           Bt1, Bt2);

    // layer 1
    agg1_kernel<<<(N_NODES + 3) / 4, 256, 0, stream>>>(xbf, aggx, cnt, slots);
    gemm_mfma_kernel<0, 1, 0><<<dim3(2, (N_NODES + 127) / 128), 256, 0, stream>>>(
        N_NODES, 256, 256, (const short*)aggx, (const short*)xbf, Bt1, b1, h, nullptr);

    // layer 2
    gemm_mfma_kernel<2, 0, 1><<<dim3(1, (N_NODES + 127) / 128), 256, 0, stream>>>(
        N_NODES, 128, 256, h, nullptr, Bt2, nullptr, grL, grR);
    final_kernel<<<(N_NODES + 3) / 4, 256, 0, stream>>>((const unsigned short*)grL,
                                                        (const unsigned short*)grR, cnt, slots,
                                                        b2, out);
}